// Round 2
// baseline (255.509 us; speedup 1.0000x reference)
//
#include <hip/hip_runtime.h>

// ExponentialUnitNorm, 2-kernel split scan (no spin, no atomics):
//   pass1: per-chunk local partials B[b,c,f]        (reads x: 123 MB HBM)
//   pass2: recompute chunk-entry state from a windowed weighted sum of
//          predecessor partials (W=24, batch-issued independent loads —
//          pass1 is complete at kernel boundary, so values are ready),
//          then rescan chunk + normalize + store.
//          x re-read comes from L3 (validated round 1: FETCH ~= x once).
// Window truncation: ALPHA_L^24 = 6.4e-5 -> ~1e-4 relative error, far
// below the bf16-quantized comparison (absmax floor 0.03125 = 1 ulp).
// Normal (cached) stores for out: x+out = 246 MB fits the 256 MB L3, and
// x is dead after pass2, so NT buys nothing; fill kernels show the normal
// store path sustains 6.7 TB/s.

#define ALPHA_F 0.99f
#define OMA_F   0.01f
#define EPS_F   1e-14f

constexpr int Bn = 16;
constexpr int Tn = 2000;
constexpr int Fn = 481;
constexpr int NC = 50;          // chunks along T
constexpr int L  = Tn / NC;     // 40
constexpr int UN = 10;          // unroll; L % UN == 0
constexpr int W  = 24;          // lookback window (aL^W = 6.4e-5)
#define ALPHA_L 0.668971758f    // 0.99^40

__global__ __launch_bounds__(256) void eun_pass1(
    const float* __restrict__ x, float* __restrict__ part) {
  const int f = blockIdx.x * blockDim.x + threadIdx.x;
  if (f >= Fn) return;
  const int b = blockIdx.y;
  const int c = blockIdx.z;

  const size_t stride = (size_t)Fn * 2;
  const float* xp = x + ((size_t)b * Tn + (size_t)c * L) * stride + (size_t)f * 2;

  float s = 0.f;
  for (int t0 = 0; t0 < L; t0 += UN) {
    float2 v[UN];
#pragma unroll
    for (int j = 0; j < UN; ++j)
      v[j] = *(const float2*)(xp + (size_t)j * stride);
#pragma unroll
    for (int j = 0; j < UN; ++j) {
      float m = sqrtf(fmaxf(fmaf(v[j].x, v[j].x, v[j].y * v[j].y), EPS_F));
      s = fmaf(ALPHA_F, s, OMA_F * m);
    }
    xp += (size_t)UN * stride;
  }
  part[((size_t)b * NC + c) * Fn + f] = s;
}

__global__ __launch_bounds__(256) void eun_pass2(
    const float* __restrict__ x, const float* __restrict__ part,
    const float* __restrict__ init_state, float* __restrict__ out) {
  const int f = blockIdx.x * blockDim.x + threadIdx.x;
  if (f >= Fn) return;
  const int b = blockIdx.y;
  const int c = blockIdx.z;

  // ---- chunk-entry state: S_c = sum_{k<min(c,W)} aL^k * B_{c-1-k}
  //                              (+ aL^c * init when c <= W, exact there) ----
  const float* pb = part + (size_t)b * NC * Fn + f;
  const int n = (c < W) ? c : W;     // uniform across block
  float pv[W];
#pragma unroll
  for (int k = 0; k < W; ++k)        // independent loads, one vmcnt batch
    if (k < n) pv[k] = pb[(size_t)(c - 1 - k) * Fn];
  float s = 0.f, w = 1.f;
#pragma unroll
  for (int k = 0; k < W; ++k)
    if (k < n) { s = fmaf(w, pv[k], s); w *= ALPHA_L; }
  if (c <= W) s = fmaf(w, init_state[f], s);   // w == aL^c here (exact)

  // ---- rescan chunk (x L3-resident), normalize, store ----
  const size_t stride = (size_t)Fn * 2;
  const size_t off = ((size_t)b * Tn + (size_t)c * L) * stride + (size_t)f * 2;
  const float* xp = x + off;
  float*       op = out + off;

  for (int t0 = 0; t0 < L; t0 += UN) {
    float2 v[UN];
#pragma unroll
    for (int j = 0; j < UN; ++j)
      v[j] = *(const float2*)(xp + (size_t)j * stride);
#pragma unroll
    for (int j = 0; j < UN; ++j) {
      float m = sqrtf(fmaxf(fmaf(v[j].x, v[j].x, v[j].y * v[j].y), EPS_F));
      s = fmaf(ALPHA_F, s, OMA_F * m);
      float inv = rsqrtf(s);
      *(float2*)(op + (size_t)j * stride) = make_float2(v[j].x * inv, v[j].y * inv);
    }
    xp += (size_t)UN * stride;
    op += (size_t)UN * stride;
  }
}

extern "C" void kernel_launch(void* const* d_in, const int* in_sizes, int n_in,
                              void* d_out, int out_size, void* d_ws, size_t ws_size,
                              hipStream_t stream) {
  const float* x    = (const float*)d_in[0];
  const float* init = (const float*)d_in[1];
  float* out        = (float*)d_out;
  float* part       = (float*)d_ws;  // Bn*NC*Fn floats = 1.54 MB

  dim3 grid((Fn + 255) / 256, Bn, NC);  // 2 x 16 x 50 = 1600 blocks
  eun_pass1<<<grid, dim3(256), 0, stream>>>(x, part);
  eun_pass2<<<grid, dim3(256), 0, stream>>>(x, part, init, out);
}